// Round 3
// baseline (737.694 us; speedup 1.0000x reference)
//
#include <hip/hip_runtime.h>
#include <stdint.h>

// PerceiverAttention on MI355X, full-bf16 MFMA pipeline.
// threshold = 2% of max|ref| (4.785e-4) -> bf16 GEMMs have ~3x margin.
// R1 fix: online-softmax rescale was applied with transposed query index
// (stats live at query=lrow, accumulator rows at query=g*4+r) -> shfl the
// scale factor across the transpose.
// R2: resubmit of R1 (GPU acquisition timeout, kernel never ran).

#define LOG2E 1.44269504088896340736f

typedef __attribute__((ext_vector_type(8))) short short8;   // 8 x bf16 (4 VGPRs)
typedef __attribute__((ext_vector_type(4))) float f32x4;

struct __align__(8) U64 { unsigned lo, hi; };

__device__ __forceinline__ uint16_t f2bf(float f) {           // RNE fp32->bf16
  uint32_t u = __float_as_uint(f);
  u += 0x7fffu + ((u >> 16) & 1u);
  return (uint16_t)(u >> 16);
}

// async global->LDS, 16B per lane; LDS dest must be wave-uniform base (lane*16 implied)
__device__ __forceinline__ void gload_lds16(const uint16_t* g, uint16_t* l) {
  auto* gp = reinterpret_cast<__attribute__((address_space(1))) uint32_t*>(
      reinterpret_cast<uintptr_t>(const_cast<uint16_t*>(g)));
  auto* lp = reinterpret_cast<__attribute__((address_space(3))) uint32_t*>(
      reinterpret_cast<uintptr_t>(l));
  __builtin_amdgcn_global_load_lds(gp, lp, 16, 0, 0);
}

// ---------------- LayerNorm + bf16 cast: one wave per 1024-wide row ----------------
__global__ __launch_bounds__(256) void ln_cast_k(
    const float* __restrict__ x, const float* __restrict__ gamma,
    const float* __restrict__ beta, uint16_t* __restrict__ out, int rows)
{
  int wid = threadIdx.x >> 6, lane = threadIdx.x & 63;
  int row = blockIdx.x * 4 + wid;
  if (row >= rows) return;
  const float4* xr = (const float4*)(x + (size_t)row * 1024);
  float4 v[4];
  float s = 0.f, s2 = 0.f;
#pragma unroll
  for (int j = 0; j < 4; ++j) {
    v[j] = xr[j * 64 + lane];
    s  += v[j].x + v[j].y + v[j].z + v[j].w;
    s2 += v[j].x * v[j].x + v[j].y * v[j].y + v[j].z * v[j].z + v[j].w * v[j].w;
  }
#pragma unroll
  for (int o = 32; o > 0; o >>= 1) { s += __shfl_xor(s, o); s2 += __shfl_xor(s2, o); }
  float mu = s * (1.f / 1024.f);
  float var = fmaxf(s2 * (1.f / 1024.f) - mu * mu, 0.f);
  float rs = rsqrtf(var + 1e-5f);
  U64* orow = (U64*)(out + (size_t)row * 1024);
#pragma unroll
  for (int j = 0; j < 4; ++j) {
    float4 gv = ((const float4*)gamma)[j * 64 + lane];
    float4 bv = ((const float4*)beta)[j * 64 + lane];
    unsigned u0 = (unsigned)f2bf((v[j].x - mu) * rs * gv.x + bv.x);
    unsigned u1 = (unsigned)f2bf((v[j].y - mu) * rs * gv.y + bv.y);
    unsigned u2 = (unsigned)f2bf((v[j].z - mu) * rs * gv.z + bv.z);
    unsigned u3 = (unsigned)f2bf((v[j].w - mu) * rs * gv.w + bv.w);
    U64 t; t.lo = u0 | (u1 << 16); t.hi = u2 | (u3 << 16);
    orow[j * 64 + lane] = t;
  }
}

// ---------------- fp32 [K][N] -> bf16 [N][K] transpose-cast (tiny weights) ----------------
__global__ __launch_bounds__(256) void tcast_k(
    const float* __restrict__ in, uint16_t* __restrict__ out, int K, int N)
{
  __shared__ float tile[32][33];
  int n0 = blockIdx.x * 32, k0 = blockIdx.y * 32;
  int tx = threadIdx.x, ty = threadIdx.y;   // block (32,8)
  for (int i = ty; i < 32; i += 8)
    tile[i][tx] = in[(size_t)(k0 + i) * N + n0 + tx];
  __syncthreads();
  for (int i = ty; i < 32; i += 8)
    out[(size_t)(n0 + i) * K + k0 + tx] = f2bf(tile[tx][i]);
}

// ---------------- bf16 GEMM: C[M][N] = alpha * A[M][K] @ BT[N][K]^T ----------------
// m97 structure: 128x128 tile, BK=32, 4 waves (2x2), global_load_lds staging, dbuf LDS.
template <int WRITE_F32>
__global__ __launch_bounds__(256, 2) void gemm_bt_k(
    const uint16_t* __restrict__ A, const uint16_t* __restrict__ BT,
    void* __restrict__ C, int M, int N, int K, float alpha)
{
  __shared__ uint16_t As[2][4096];
  __shared__ uint16_t Bs[2][4096];
  int NT = N >> 7;
  int mt = blockIdx.x / NT, nt = blockIdx.x % NT;
  int tid = threadIdx.x;
  int wid = tid >> 6, lane = tid & 63;
  int lrow = lane & 15, g = lane >> 4;
  int wr = wid >> 1, wc = wid & 1;
  const uint16_t* Ab = A + (size_t)mt * 128 * K;
  const uint16_t* Bb = BT + (size_t)nt * 128 * K;
  f32x4 acc[4][4];
#pragma unroll
  for (int i = 0; i < 4; ++i)
#pragma unroll
    for (int j = 0; j < 4; ++j)
#pragma unroll
      for (int r = 0; r < 4; ++r) acc[i][j][r] = 0.f;

  auto stage = [&](int buf, int k0) {
#pragma unroll
    for (int r = 0; r < 2; ++r) {
      int c2 = wid * 2 + r;                       // chunk: 16 rows, 1024B of LDS
      size_t go = (size_t)(c2 * 16 + (lane >> 2)) * K + k0 + (lane & 3) * 8;
      gload_lds16(Ab + go, &As[buf][c2 * 512]);
      gload_lds16(Bb + go, &Bs[buf][c2 * 512]);
    }
  };
  int nk = K >> 5;
  stage(0, 0);
  for (int kt = 0; kt < nk; ++kt) {
    __syncthreads();                              // drains vmcnt for buf kt&1
    if (kt + 1 < nk) stage((kt + 1) & 1, (kt + 1) * 32);
    const uint16_t* as_ = As[kt & 1];
    const uint16_t* bs_ = Bs[kt & 1];
    short8 af[4], bf_[4];
#pragma unroll
    for (int i = 0; i < 4; ++i) {
      af[i]  = *(const short8*)&as_[(wr * 64 + i * 16 + lrow) * 32 + g * 8];
      bf_[i] = *(const short8*)&bs_[(wc * 64 + i * 16 + lrow) * 32 + g * 8];
    }
#pragma unroll
    for (int i = 0; i < 4; ++i)
#pragma unroll
      for (int j = 0; j < 4; ++j)
        acc[i][j] = __builtin_amdgcn_mfma_f32_16x16x32_bf16(af[i], bf_[j], acc[i][j], 0, 0, 0);
  }
  size_t row0 = (size_t)mt * 128 + wr * 64;
  size_t col0 = (size_t)nt * 128 + wc * 64;
#pragma unroll
  for (int i = 0; i < 4; ++i)
#pragma unroll
    for (int j = 0; j < 4; ++j)
#pragma unroll
      for (int r = 0; r < 4; ++r) {
        size_t row = row0 + i * 16 + g * 4 + r;   // C/D: col=lane&15, row=(lane>>4)*4+reg
        size_t col = col0 + j * 16 + lrow;
        float vv = acc[i][j][r] * alpha;
        if (WRITE_F32) ((float*)C)[row * N + col] = vv;
        else           ((uint16_t*)C)[row * N + col] = f2bf(vv);
      }
}

// ---------------- flash attention: one block per (b,h), 8 waves split n ----------------
// q: [512][512] bf16 (rows b*64+l, cols h*64+d), already scaled by 0.125*log2e.
// kv: [65536][1024] bf16 (rows b*8192+n; cols: k at h*64+d, v at 512+h*64+d).
// attn_out: [512][512] bf16 normalized output.
__global__ __launch_bounds__(512) void attn_k(
    const uint16_t* __restrict__ q, const uint16_t* __restrict__ kv,
    uint16_t* __restrict__ attn_out)
{
  __shared__ float lds_o[8 * 64 * 64];     // 128 KB: per-wave partial O
  __shared__ float lds_m[8 * 64];
  __shared__ float lds_l[8 * 64];
  __shared__ uint16_t pst_all[8 * 512];    // per-wave P stash [16 l][32 n]
  int bh = blockIdx.x, b = bh >> 3, h = bh & 7;
  int wid = threadIdx.x >> 6, lane = threadIdx.x & 63;
  int lrow = lane & 15, g = lane >> 4;
  uint16_t* pst = pst_all + wid * 512;
  const uint16_t* qb = q + (size_t)b * 64 * 512 + h * 64;
  const uint16_t* kb = kv + (size_t)b * 8192 * 1024 + h * 64;
  const uint16_t* vb = kb + 512;
  short8 qf[4][2];                          // Q B-frags: Q[lb*16+lrow][ks*32+g*8+j]
#pragma unroll
  for (int lb = 0; lb < 4; ++lb)
#pragma unroll
    for (int ks = 0; ks < 2; ++ks)
      qf[lb][ks] = *(const short8*)(qb + (size_t)(lb * 16 + lrow) * 512 + ks * 32 + g * 8);
  f32x4 acc_o[4][4];                        // [lb][db]; row(query)=g*4+r, col(d)=db*16+lrow
  float m_run[4], l_run[4];                 // stats for query = lb*16 + lrow
#pragma unroll
  for (int lb = 0; lb < 4; ++lb) {
    m_run[lb] = -3e38f; l_run[lb] = 0.f;
#pragma unroll
    for (int db = 0; db < 4; ++db)
#pragma unroll
      for (int r = 0; r < 4; ++r) acc_o[lb][db][r] = 0.f;
  }
  for (int t = 0; t < 32; ++t) {            // each wave: 1024 n-rows, 32-row tiles
    int n0 = wid * 1024 + t * 32;
    short8 ak[2][2];                        // K A-frags
#pragma unroll
    for (int nt2 = 0; nt2 < 2; ++nt2)
#pragma unroll
      for (int ks = 0; ks < 2; ++ks)
        ak[nt2][ks] = *(const short8*)(kb + (size_t)(n0 + nt2 * 16 + lrow) * 1024 + ks * 32 + g * 8);
    short8 bv[4];                           // V B-frags: V[n0+g*8+j][db*16+lrow]
#pragma unroll
    for (int db = 0; db < 4; ++db) {
      short8 sv;
#pragma unroll
      for (int jj = 0; jj < 8; ++jj)
        sv[jj] = (short)vb[(size_t)(n0 + g * 8 + jj) * 1024 + db * 16 + lrow];
      bv[db] = sv;
    }
#pragma unroll
    for (int lb = 0; lb < 4; ++lb) {
      f32x4 s0, s1;                         // sim^T: rows=n, cols=l (swapped QK)
#pragma unroll
      for (int r = 0; r < 4; ++r) { s0[r] = 0.f; s1[r] = 0.f; }
      s0 = __builtin_amdgcn_mfma_f32_16x16x32_bf16(ak[0][0], qf[lb][0], s0, 0, 0, 0);
      s0 = __builtin_amdgcn_mfma_f32_16x16x32_bf16(ak[0][1], qf[lb][1], s0, 0, 0, 0);
      s1 = __builtin_amdgcn_mfma_f32_16x16x32_bf16(ak[1][0], qf[lb][0], s1, 0, 0, 0);
      s1 = __builtin_amdgcn_mfma_f32_16x16x32_bf16(ak[1][1], qf[lb][1], s1, 0, 0, 0);
      float tm = fmaxf(fmaxf(fmaxf(s0[0], s0[1]), fmaxf(s0[2], s0[3])),
                       fmaxf(fmaxf(s1[0], s1[1]), fmaxf(s1[2], s1[3])));
      tm = fmaxf(tm, __shfl_xor(tm, 16));   // reduce over the 4 g-groups
      tm = fmaxf(tm, __shfl_xor(tm, 32));
      float mn = fmaxf(m_run[lb], tm);
      float sc = exp2f(m_run[lb] - mn);     // rescale for query = lrow
      // R1 FIX: acc_o rows are query g*4+r, not lrow. Fetch those queries'
      // scale factors from lanes g*4+r (which have lrow == g*4+r, g==0).
      float scr[4];
#pragma unroll
      for (int r = 0; r < 4; ++r) scr[r] = __shfl(sc, g * 4 + r);
      float p[8], ts = 0.f;
#pragma unroll
      for (int r = 0; r < 4; ++r) {
        p[r]     = exp2f(s0[r] - mn);
        p[r + 4] = exp2f(s1[r] - mn);
        ts += p[r] + p[r + 4];
      }
      ts += __shfl_xor(ts, 16);
      ts += __shfl_xor(ts, 32);
      l_run[lb] = l_run[lb] * sc + ts;
      m_run[lb] = mn;
#pragma unroll
      for (int db = 0; db < 4; ++db)
#pragma unroll
        for (int r = 0; r < 4; ++r) acc_o[lb][db][r] *= scr[r];
      // P -> bf16 stash [l][n] (wave-private; DS in-order per wave, no barrier needed)
      U64 w0, w1;
      w0.lo = (unsigned)f2bf(p[0]) | ((unsigned)f2bf(p[1]) << 16);
      w0.hi = (unsigned)f2bf(p[2]) | ((unsigned)f2bf(p[3]) << 16);
      w1.lo = (unsigned)f2bf(p[4]) | ((unsigned)f2bf(p[5]) << 16);
      w1.hi = (unsigned)f2bf(p[6]) | ((unsigned)f2bf(p[7]) << 16);
      *(U64*)&pst[lrow * 32 + g * 4]      = w0;   // nt2=0: n = g*4+r
      *(U64*)&pst[lrow * 32 + 16 + g * 4] = w1;   // nt2=1: n = 16+g*4+r
      asm volatile("" ::: "memory");               // keep write->read order in codegen
      short8 ap = *(const short8*)&pst[lrow * 32 + g * 8];  // P A-frag: P[lrow][g*8+j]
#pragma unroll
      for (int db = 0; db < 4; ++db)
        acc_o[lb][db] = __builtin_amdgcn_mfma_f32_16x16x32_bf16(ap, bv[db], acc_o[lb][db], 0, 0, 0);
    }
  }
  // merge 8 wave-partials
  if (g == 0) {
#pragma unroll
    for (int lb = 0; lb < 4; ++lb) {
      lds_m[wid * 64 + lb * 16 + lrow] = m_run[lb];
      lds_l[wid * 64 + lb * 16 + lrow] = l_run[lb];
    }
  }
#pragma unroll
  for (int lb = 0; lb < 4; ++lb)
#pragma unroll
    for (int db = 0; db < 4; ++db)
#pragma unroll
      for (int r = 0; r < 4; ++r)
        lds_o[((wid * 64 + lb * 16 + g * 4 + r) << 6) + db * 16 + lrow] = acc_o[lb][db][r];
  __syncthreads();
  {
    int l = threadIdx.x & 63, part = threadIdx.x >> 6;
    float Mv = -3e38f;
#pragma unroll
    for (int w = 0; w < 8; ++w) Mv = fmaxf(Mv, lds_m[w * 64 + l]);
    float ew[8], L = 0.f;
#pragma unroll
    for (int w = 0; w < 8; ++w) {
      ew[w] = exp2f(lds_m[w * 64 + l] - Mv);
      L += lds_l[w * 64 + l] * ew[w];
    }
    float rL = 1.f / L;
#pragma unroll
    for (int dd = 0; dd < 8; ++dd) {
      int d = part * 8 + dd;
      float O = 0.f;
#pragma unroll
      for (int w = 0; w < 8; ++w) O += lds_o[((w * 64 + l) << 6) + d] * ew[w];
      attn_out[(size_t)(b * 64 + l) * 512 + h * 64 + d] = f2bf(O * rL);
    }
  }
}

extern "C" void kernel_launch(void* const* d_in, const int* in_sizes, int n_in,
                              void* d_out, int out_size, void* d_ws, size_t ws_size,
                              hipStream_t stream)
{
  const float* x    = (const float*)d_in[0];
  const float* lat  = (const float*)d_in[1];
  const float* g1   = (const float*)d_in[2];
  const float* b1   = (const float*)d_in[3];
  const float* g2   = (const float*)d_in[4];
  const float* b2   = (const float*)d_in[5];
  const float* Wq   = (const float*)d_in[6];
  const float* Wkv  = (const float*)d_in[7];
  const float* Wout = (const float*)d_in[8];
  float* out = (float*)d_out;
  char* ws = (char*)d_ws;

  const size_t SZ_XN = (size_t)65536 * 1024 * 2;   // 128 MB
  const size_t MB = 1u << 20;
  uint16_t* xn    = (uint16_t*)(ws);                       // [65536][1024] bf16
  uint16_t* kvb   = (uint16_t*)(ws + SZ_XN);               // [65536][1024] bf16
  uint16_t* WqT   = (uint16_t*)(ws + 2 * SZ_XN);           // [512][1024]
  uint16_t* WkvT  = (uint16_t*)(ws + 2 * SZ_XN + 1 * MB);  // [1024][1024]
  uint16_t* WoutT = (uint16_t*)(ws + 2 * SZ_XN + 3 * MB);  // [1024][512]
  uint16_t* qb    = (uint16_t*)(ws + 2 * SZ_XN + 4 * MB);  // [512][512]
  uint16_t* ao    = (uint16_t*)(ws + 2 * SZ_XN + 5 * MB);  // [512][512]
  uint16_t* lnb   = (uint16_t*)(ws + 2 * SZ_XN + 6 * MB);  // [512][1024]
  size_t need = 2 * SZ_XN + 7 * MB;
  if (ws_size < need) {                                    // diagnosable sentinel: NaN output
    hipMemsetAsync(d_out, 0xFF, (size_t)out_size * 4, stream);
    return;
  }

  // weights -> bf16 [N][K]
  tcast_k<<<dim3(16, 32), dim3(32, 8), 0, stream>>>(Wq,   WqT,   1024, 512);
  tcast_k<<<dim3(32, 32), dim3(32, 8), 0, stream>>>(Wkv,  WkvT,  1024, 1024);
  tcast_k<<<dim3(32, 16), dim3(32, 8), 0, stream>>>(Wout, WoutT, 512,  1024);
  // layernorms
  ln_cast_k<<<16384, 256, 0, stream>>>(x,   g1, b1, xn,  65536);
  ln_cast_k<<<128,   256, 0, stream>>>(lat, g2, b2, lnb, 512);
  // q = ln(latents) @ Wq, scale (dh^-0.5) and log2e folded in (softmax uses exp2)
  gemm_bt_k<0><<<16,   256, 0, stream>>>(lnb, WqT,  qb,  512,   512,  1024, 0.125f * LOG2E);
  // kv = ln(x) @ Wkv  (the 137 GFLOP GEMM)
  gemm_bt_k<0><<<4096, 256, 0, stream>>>(xn,  WkvT, kvb, 65536, 1024, 1024, 1.0f);
  // attention
  attn_k<<<64, 512, 0, stream>>>(qb, kvb, ao);
  // final projection, fp32 out
  gemm_bt_k<1><<<32,   256, 0, stream>>>(ao,  WoutT, out, 512,  1024, 512,  1.0f);
}